// Round 5
// baseline (69.208 us; speedup 1.0000x reference)
//
#include <hip/hip_runtime.h>

#define B_SZ 16384
#define N_SP 129
#define GRID 256
#define BLOCK 512

typedef _Float16 half8 __attribute__((ext_vector_type(8)));
typedef float float4v __attribute__((ext_vector_type(4)));

// Only cross-kernel state: per-block penalty partials (device globals,
// d_ws untouched). Visibility main->reduce is via the dispatch boundary.
__device__ float g_p1[GRID];
__device__ float g_p2[GRID];

// index into main_w for quadratic pair (i<j), N=129: N + i*(2N-i-1)/2 + (j-i-1)
__device__ __forceinline__ int qidx(int i, int j) {
  return N_SP + i * (2 * N_SP - i - 1) / 2 + (j - i - 1);
}

// tanh(x) = 1 - 2/(e^{2x}+1): monotone, stable both tails
__device__ __forceinline__ float fast_tanh(float x) {
  float xc = fminf(fmaxf(x, -15.f), 15.f);
  float e = __expf(2.f * xc);
  return 1.f - 2.f / (e + 1.f);
}

// R5 structure: 256 blocks x 64 rows, BLOCK=512 (8 waves, 1 block/CU).
// Waves 0-3 own tiles 0-1, waves 4-7 own tiles 2-3; within a wave-group,
// wave (wib&3) owns unit slice u = (wib&3)*16 + m. One table staging
// (bit-identical values to R3/R4) now amortized over 64 rows; 8 waves/CU
// preserve latency hiding through the post-poison cold staging phase.
__global__ __launch_bounds__(BLOCK, 1) void main_kernel(
    const float* __restrict__ inps, const float* __restrict__ tw,
    const float* __restrict__ tb, const float* __restrict__ mw,
    float* __restrict__ out) {
  __shared__ __align__(16) _Float16 s_tw[64 * 72];   // 9216 B
  __shared__ __align__(16) _Float16 s_qxt[64 * 72];  // 9216 B
  __shared__ __align__(16) _Float16 s_qtt[64 * 72];  // 9216 B
  __shared__ __align__(16) _Float16 s_x[64 * 72];    // 64 rows x stride 72
  __shared__ __align__(16) _Float16 s_dt[64 * 72];
  __shared__ float s_part[256];                      // [tile 0..3][us*16+row]
  __shared__ float s_red[16];

  const int tid = threadIdx.x;
  const int l = tid & 63, wib = tid >> 6;            // wib 0..7
  const int us = wib & 3, tp = (wib >> 2) << 1;      // unit-slice, first tile
  const int b0 = blockIdx.x << 6;                    // 64 rows/block
  const int q = l >> 4, m = l & 15;
  const int u = (us << 4) + m;                       // this lane's unit / i index

  // ---- x staging: 64 rows x 65 f32 = 1040 float4 -> s_x f16 [64][72] ----
  {
    const float4* src4 = (const float4*)(inps + b0 * 65);  // 16640 B/block, 16B-aligned
#pragma unroll
    for (int s = 0; s < 2; s++) {
      float4 v = src4[tid + 512 * s];
#pragma unroll
      for (int c = 0; c < 4; c++) {
        unsigned idx = (tid + 512 * s) * 4 + c;
        unsigned row = idx / 65u, col = idx - row * 65u;
        s_x[row * 72 + col] = (_Float16)((const float*)&v)[c];
      }
    }
    if (tid < 16) {
      float4 v = src4[1024 + tid];
#pragma unroll
      for (int c = 0; c < 4; c++) {
        unsigned idx = (1024 + tid) * 4 + c;
        unsigned row = idx / 65u, col = idx - row * 65u;
        s_x[row * 72 + col] = (_Float16)((const float*)&v)[c];
      }
    }
  }

  // ---- tw staging: 64x65 f32 = 1040 float4 -> s_tw [64][72] ----
  {
    const float4* src4 = (const float4*)tw;
#pragma unroll
    for (int s = 0; s < 2; s++) {
      float4 v = src4[tid + 512 * s];
#pragma unroll
      for (int c = 0; c < 4; c++) {
        unsigned idx = (tid + 512 * s) * 4 + c;
        unsigned row = idx / 65u, col = idx - row * 65u;
        s_tw[row * 72 + col] = (_Float16)((const float*)&v)[c];
      }
    }
    if (tid < 16) {
      float4 v = src4[1024 + tid];
#pragma unroll
      for (int c = 0; c < 4; c++) {
        unsigned idx = (1024 + tid) * 4 + c;
        unsigned row = idx / 65u, col = idx - row * 65u;
        s_tw[row * 72 + col] = (_Float16)((const float*)&v)[c];
      }
    }
  }

  // ---- qxt staging: 4096 elems, dst-linear (each wave = contiguous rows) ----
  // Qxt[i][k] = mw[qidx(i,65)+k]; qidx(i,65) = 193 + i*(257-i)/2 - i
  {
#pragma unroll
    for (int s = 0; s < 8; s++) {
      int d = tid + 512 * s;
      int i = d >> 6, k = d & 63;
      int src = 193 + ((i * (257 - i)) >> 1) - i + k;
      s_qxt[i * 72 + k] = (_Float16)mw[src];
    }
  }

  // ---- qtt staging: packed strict-upper triangle (2016 f32 at mw+6369),
  //      8 consecutive elems/thread, scatter to both (a,b) and (b,a) ----
  {
    if (tid < 252) {
      const float* srcp = mw + 6369 + tid * 8;
      float v[8];
#pragma unroll
      for (int e = 0; e < 8; e++) v[e] = srcp[e];
      int p0 = tid * 8;
      int a = (int)((127.0f - sqrtf((float)(16129 - 8 * p0))) * 0.5f);
      if (a < 0) a = 0;
      if (a > 62) a = 62;
      while (a > 0 && (a * (127 - a)) / 2 > p0) --a;
      while (a < 62 && ((a + 1) * (126 - a)) / 2 <= p0) ++a;
      int b = a + 1 + (p0 - (a * (127 - a)) / 2);
#pragma unroll
      for (int e = 0; e < 8; e++) {
        _Float16 h = (_Float16)v[e];
        s_qtt[a * 72 + b] = h;
        s_qtt[b * 72 + a] = h;
        if (++b > 63) { ++a; b = a + 1; }
      }
    }
    if (tid < 64) s_qtt[tid * 72 + tid] = (_Float16)0.f;
  }

  // ---- per-lane coefficients: direct scalar loads (full f32) ----
  const float twyv = tw[u * 65 + 64];
  const float qxyv = mw[qidx(u, 64)];
  const float qytv = mw[qidx(64, 65 + u)];
  const float lintv = mw[65 + u];
  const float liny = mw[64];
  const float tbv = tb[u];

  __syncthreads();  // all LDS tables + x tiles ready

  // B-frags for phase 1 (per-u; shared across this wave's two tiles)
  half8 bt0 = *(const half8*)(s_tw + u * 72 + q * 8);
  half8 bt1 = *(const half8*)(s_tw + u * 72 + 32 + q * 8);

  // ---- phase 1: two tiles — first matvec, tanh pair, dt tiles, penalties ----
  float yv[2][4], dtv[2][4], stv[2][4];
  float pint = 0.f, pneut = 0.f;
#pragma unroll
  for (int itl = 0; itl < 2; itl++) {
    const int rb = (tp + itl) << 4;
    half8 ax0 = *(const half8*)(s_x + (rb + m) * 72 + q * 8);
    half8 ax1 = *(const half8*)(s_x + (rb + m) * 72 + 32 + q * 8);
    float4v acc = {0.f, 0.f, 0.f, 0.f};
    acc = __builtin_amdgcn_mfma_f32_16x16x32_f16(ax0, bt0, acc, 0, 0, 0);
    acc = __builtin_amdgcn_mfma_f32_16x16x32_f16(ax1, bt1, acc, 0, 0, 0);
#pragma unroll
    for (int r = 0; r < 4; r++) {
      yv[itl][r] = (float)s_x[(rb + q * 4 + r) * 72 + 64];
      float wpre = acc[r] + tbv;
      float w1 = wpre + twyv * yv[itl][r];
      float w2 = wpre - twyv * yv[itl][r];
      float t1 = fast_tanh(w1), t2 = fast_tanh(w2);
      dtv[itl][r] = t1 - t2; stv[itl][r] = t1 + t2;
      float a1 = 1.f - t1 * t1, a2 = 1.f - t2 * t2;
      pint += a1 * a1 + a2 * a2;
      float nv = t2 * w2 - t1 * w1;
      pneut += nv * nv;
      s_dt[(rb + q * 4 + r) * 72 + u] = (_Float16)dtv[itl][r];
    }
  }
  __syncthreads();

  // B-frags for phase 2 (per-u; shared across this wave's two tiles)
  half8 bq0 = *(const half8*)(s_qxt + u * 72 + q * 8);
  half8 bq1 = *(const half8*)(s_qxt + u * 72 + 32 + q * 8);
  half8 bs0 = *(const half8*)(s_qtt + u * 72 + q * 8);
  half8 bs1 = *(const half8*)(s_qtt + u * 72 + 32 + q * 8);

  // ---- phase 2: two tiles — 4 matvecs each, per-row contributions ----
#pragma unroll
  for (int itl = 0; itl < 2; itl++) {
    const int it = tp + itl;
    const int rb = it << 4;
    half8 ad0 = *(const half8*)(s_dt + (rb + m) * 72 + q * 8);
    half8 ad1 = *(const half8*)(s_dt + (rb + m) * 72 + 32 + q * 8);
    float4v rxt = {0.f, 0.f, 0.f, 0.f}, rtt = {0.f, 0.f, 0.f, 0.f};
    rxt = __builtin_amdgcn_mfma_f32_16x16x32_f16(ad0, bq0, rxt, 0, 0, 0);
    rxt = __builtin_amdgcn_mfma_f32_16x16x32_f16(ad1, bq1, rxt, 0, 0, 0);
    rtt = __builtin_amdgcn_mfma_f32_16x16x32_f16(ad0, bs0, rtt, 0, 0, 0);
    rtt = __builtin_amdgcn_mfma_f32_16x16x32_f16(ad1, bs1, rtt, 0, 0, 0);
#pragma unroll
    for (int r = 0; r < 4; r++) {
      float xv = (float)s_x[(rb + q * 4 + r) * 72 + u];
      float c = xv * (2.f * yv[itl][r] * qxyv + rxt[r])
              + yv[itl][r] * stv[itl][r] * qytv
              + 0.5f * stv[itl][r] * rtt[r]
              + lintv * dtv[itl][r];
      c += __shfl_xor(c, 1); c += __shfl_xor(c, 2);
      c += __shfl_xor(c, 4); c += __shfl_xor(c, 8);
      if (m == 0) s_part[it * 64 + us * 16 + q * 4 + r] = c;
    }
  }

  // penalties: one wave reduce across both tiles -> per-wave partial
#pragma unroll
  for (int off = 1; off < 64; off <<= 1) {
    pint += __shfl_xor(pint, off);
    pneut += __shfl_xor(pneut, off);
  }
  if (l == 0) { s_red[wib] = pint; s_red[8 + wib] = pneut; }
  __syncthreads();

  if (tid < 64) {
    const int it = tid >> 4, t = tid & 15;
    float c = s_part[it * 64 + t] + s_part[it * 64 + 16 + t]
            + s_part[it * 64 + 32 + t] + s_part[it * 64 + 48 + t];
    float y = (float)s_x[tid * 72 + 64];
    out[b0 + tid] = 1.f + 2.f * y * liny + c;
  }
  if (tid == 0) {
    float a = 0.f, b = 0.f;
#pragma unroll
    for (int i = 0; i < 8; i++) { a += s_red[i]; b += s_red[8 + i]; }
    g_p1[blockIdx.x] = a;
    g_p2[blockIdx.x] = b;
  }
}

__global__ __launch_bounds__(256) void reduce_kernel(float* __restrict__ out) {
  __shared__ float s[8];
  const int tid = threadIdx.x;
  float a = g_p1[tid];
  float b = g_p2[tid];
#pragma unroll
  for (int off = 1; off < 64; off <<= 1) {
    a += __shfl_xor(a, off);
    b += __shfl_xor(b, off);
  }
  const int w = tid >> 6, l = tid & 63;
  if (l == 0) { s[w] = a; s[4 + w] = b; }
  __syncthreads();
  if (tid == 0) {
    float sa = 0.f, sb = 0.f;
#pragma unroll
    for (int i = 0; i < 4; i++) { sa += s[i]; sb += s[4 + i]; }
    out[B_SZ] = sa * (1.f / 300.f);
    out[B_SZ + 1] = sb;
  }
}

extern "C" void kernel_launch(void* const* d_in, const int* in_sizes, int n_in,
                              void* d_out, int out_size, void* d_ws, size_t ws_size,
                              hipStream_t stream) {
  const float* inps = (const float*)d_in[0];
  const float* tw   = (const float*)d_in[1];
  const float* tb   = (const float*)d_in[2];
  const float* mw   = (const float*)d_in[3];
  float* out = (float*)d_out;
  (void)d_ws; (void)ws_size;  // workspace deliberately untouched
  main_kernel<<<GRID, BLOCK, 0, stream>>>(inps, tw, tb, mw, out);
  reduce_kernel<<<1, 256, 0, stream>>>(out);
}